// Round 5
// baseline (1212.124 us; speedup 1.0000x reference)
//
#include <hip/hip_runtime.h>

#define PAD_IDX 0

typedef __attribute__((ext_vector_type(8))) short short8;
typedef __attribute__((ext_vector_type(4))) float f32x4;

// ---------- helpers ----------
__device__ __forceinline__ unsigned short f32_to_bf16_rne(float f) {
  unsigned int u = __builtin_bit_cast(unsigned int, f);
  u += 0x7FFFu + ((u >> 16) & 1u);
  return (unsigned short)(u >> 16);
}

__device__ __forceinline__ void load16_to_lds(const void* g, void* lds) {
  __builtin_amdgcn_global_load_lds(
      (const __attribute__((address_space(1))) unsigned int*)g,
      (__attribute__((address_space(3))) unsigned int*)lds,
      16, 0, 0);
}

// ---------- kernel 0: sentinel (only if ws too small) ----------
__global__ void sentinel_kernel(float* out) { out[0] = 1.0e6f; }

// ---------- kernel 1: lm_W f32 -> bf16 ----------
__global__ __launch_bounds__(256) void cvt_kernel(const float* __restrict__ in,
                                                  unsigned short* __restrict__ out,
                                                  int n8) {
  int stride = gridDim.x * blockDim.x;
  for (int i = blockIdx.x * blockDim.x + threadIdx.x; i < n8; i += stride) {
    float4 a = ((const float4*)in)[2 * i];
    float4 b = ((const float4*)in)[2 * i + 1];
    ushort4 lo, hi;
    lo.x = f32_to_bf16_rne(a.x); lo.y = f32_to_bf16_rne(a.y);
    lo.z = f32_to_bf16_rne(a.z); lo.w = f32_to_bf16_rne(a.w);
    hi.x = f32_to_bf16_rne(b.x); hi.y = f32_to_bf16_rne(b.y);
    hi.z = f32_to_bf16_rne(b.z); hi.w = f32_to_bf16_rne(b.w);
    ((ushort4*)out)[2 * i] = lo;
    ((ushort4*)out)[2 * i + 1] = hi;
  }
}

// ---------- kernel 2: xw[r][j] = emb[tok[r]] . Wx[j] + bias[j]  (f32) ----------
__global__ __launch_bounds__(256) void xw_kernel(const int* __restrict__ tok,
                                                 const float* __restrict__ emb,
                                                 const float* __restrict__ Wx,
                                                 const float* __restrict__ bias,
                                                 float* __restrict__ xw) {
  __shared__ float At[32][68];  // [k][m], padded
  __shared__ float Bt[32][68];  // [k][n]
  __shared__ int stok[64];
  int tid = threadIdx.x;
  int tm = blockIdx.x & 63;
  int tn = blockIdx.x >> 6;
  int r0 = tm * 64, j0 = tn * 64;
  if (tid < 64) stok[tid] = tok[r0 + tid];
  int tx = tid & 15, ty = tid >> 4;
  float acc[4][4] = {};
  for (int kt = 0; kt < 512; kt += 32) {
    __syncthreads();
    #pragma unroll
    for (int ii = 0; ii < 2; ++ii) {
      int idx = tid * 2 + ii;
      int m = idx >> 3, fv = idx & 7;
      float4 va = *(const float4*)&emb[(size_t)stok[m] * 512 + kt + fv * 4];
      float4 vb = *(const float4*)&Wx[(size_t)(j0 + m) * 512 + kt + fv * 4];
      At[fv * 4 + 0][m] = va.x; At[fv * 4 + 1][m] = va.y;
      At[fv * 4 + 2][m] = va.z; At[fv * 4 + 3][m] = va.w;
      Bt[fv * 4 + 0][m] = vb.x; Bt[fv * 4 + 1][m] = vb.y;
      Bt[fv * 4 + 2][m] = vb.z; Bt[fv * 4 + 3][m] = vb.w;
    }
    __syncthreads();
    #pragma unroll
    for (int k = 0; k < 32; ++k) {
      float4 a4 = *(const float4*)&At[k][ty * 4];
      float4 b4 = *(const float4*)&Bt[k][tx * 4];
      float av[4] = {a4.x, a4.y, a4.z, a4.w};
      float bv[4] = {b4.x, b4.y, b4.z, b4.w};
      #pragma unroll
      for (int i = 0; i < 4; ++i)
        #pragma unroll
        for (int jj = 0; jj < 4; ++jj) acc[i][jj] = fmaf(av[i], bv[jj], acc[i][jj]);
    }
  }
  #pragma unroll
  for (int i = 0; i < 4; ++i) {
    size_t row = (size_t)(r0 + ty * 4 + i) * 1024 + j0 + tx * 4;
    #pragma unroll
    for (int jj = 0; jj < 4; ++jj)
      xw[row + jj] = acc[i][jj] + bias[j0 + tx * 4 + jj];
  }
}

// ---------- kernel 3: recurrence ----------
// 256 WGs x 1024 threads. chain c = blk&15 (all WGs of chain c on XCD c%8 under
// round-robin), wg g = blk>>4 owns rows g*64..+63. Thread (row=tid>>4, kk=tid&15):
// k-slice kk*64..+63. Sync: FUSED data+tag u64 {tag,h_bits}, parity double-buffer.
// R5 deltas: hs parity double-buffer drops the 2nd barrier (reuse ordered through
// barrier1 + cross-WG tag dependency chain); poll has no s_sleep.
__global__ __launch_bounds__(1024, 4) void rec_kernel(const float* __restrict__ Wh,
                                                      const float* __restrict__ xw,
                                                      const int* __restrict__ tok,
                                                      unsigned long long* hcomb,  // [2][16][1024]
                                                      unsigned short* __restrict__ h_all) {
  int c = blockIdx.x & 15;
  int g = blockIdx.x >> 4;
  int tid = threadIdx.x;
  int kk = tid & 15;
  int j = g * 64 + (tid >> 4);

  const float* wb = Wh + (size_t)j * 1024 + kk * 64;
#define LDW(i) f32x4 w##i = *(const f32x4*)(wb + i * 4);
  LDW(0) LDW(1) LDW(2) LDW(3) LDW(4) LDW(5) LDW(6) LDW(7)
  LDW(8) LDW(9) LDW(10) LDW(11) LDW(12) LDW(13) LDW(14) LDW(15)
#undef LDW

  __shared__ float hs[2][16 * 68];  // parity double-buffer, padded slices
  int lidx = (tid >> 6) * 68 + (tid & 63);
  unsigned long long* hc0 = hcomb + (size_t)c * 1024;
  unsigned long long* hc1 = hcomb + 16 * 1024 + (size_t)c * 1024;
  bool writer = (kk == 0);

  for (int t = 0; t < 256; ++t) {
    int p = t & 1;
    float xv = 0.f;
    int tkn = 1;
    size_t rowoff = ((size_t)c * 256 + t) * 1024 + j;
    if (writer) {
      xv = xw[rowoff];
      tkn = tok[c * 256 + t];
    }
    unsigned long long* src = (p ? hc1 : hc0) + tid;
    unsigned long long v;
    int guard = 0;
    do {
      v = __hip_atomic_load(src, __ATOMIC_RELAXED, __HIP_MEMORY_SCOPE_AGENT);
      if ((unsigned int)(v >> 32) == (unsigned int)t) break;
    } while (++guard < (1 << 22));  // fail loud (absmax), not hung
    hs[p][lidx] = __builtin_bit_cast(float, (unsigned int)v);
    __asm__ volatile("s_waitcnt lgkmcnt(0)\n\ts_barrier" ::: "memory");

    const float* hp = hs[p] + kk * 68;
    f32x4 a0 = {0.f, 0.f, 0.f, 0.f}, a1 = a0, a2 = a0, a3 = a0;
#define FMAI(i, acc) { f32x4 h4 = *(const f32x4*)(hp + i * 4); acc += w##i * h4; }
    FMAI(0, a0) FMAI(1, a1) FMAI(2, a2) FMAI(3, a3)
    FMAI(4, a0) FMAI(5, a1) FMAI(6, a2) FMAI(7, a3)
    FMAI(8, a0) FMAI(9, a1) FMAI(10, a2) FMAI(11, a3)
    FMAI(12, a0) FMAI(13, a1) FMAI(14, a2) FMAI(15, a3)
#undef FMAI
    f32x4 aa = (a0 + a1) + (a2 + a3);
    float s = (aa[0] + aa[1]) + (aa[2] + aa[3]);
    s += __shfl_xor(s, 1);
    s += __shfl_xor(s, 2);
    s += __shfl_xor(s, 4);
    s += __shfl_xor(s, 8);

    if (writer) {
      float hnew;
      if (tkn != PAD_IDX) {
        float pre = xv + s;
        float e = __builtin_amdgcn_exp2f(pre * 2.8853900817779268f);  // exp(2x)
        hnew = 1.0f - 2.0f / (e + 1.0f);                              // tanh(x)
      } else {
        hnew = hs[p][(j >> 6) * 68 + (j & 63)];
      }
      unsigned long long pv =
          ((unsigned long long)(unsigned int)(t + 1) << 32) |
          (unsigned long long)__builtin_bit_cast(unsigned int, hnew);
      __hip_atomic_store((((t + 1) & 1) ? hc1 : hc0) + j, pv,
                         __ATOMIC_RELAXED, __HIP_MEMORY_SCOPE_AGENT);
      h_all[rowoff] = f32_to_bf16_rne(hnew);
    }
    // no trailing barrier: next iter writes hs[p^1]; reuse of hs[p] (t+2) is
    // ordered by barrier1(t+1) arrival -> local stores -> tag(t+1) -> poll.
  }
}

// ---------- kernel 4: logits = h_all(bf16) @ lm_W(bf16)^T, f32 out ----------
// BM=256 BN=128 BK=64. 512 thr (8 waves, 4M x 2N; per-wave 64x64). 3 LDS buffers
// (144 KB), 3-tile-deep global_load_lds pipeline, ONE s_waitcnt vmcnt(6) + raw
// s_barrier per K-tile (counted vmcnt, never 0 in loop), setprio around MFMA.
__global__ __launch_bounds__(512) void gemm_kernel(const unsigned short* __restrict__ A,
                                                   const unsigned short* __restrict__ B,
                                                   float* __restrict__ C) {
  __shared__ unsigned short lds[3 * 24576];  // 3 x (A:16384 + B:8192 shorts) = 144 KB
  int tid = threadIdx.x;
  int lane = tid & 63, wave = tid >> 6;
  int bid = blockIdx.x;
  int wgid = (bid & 7) * 500 + (bid >> 3);   // bijective XCD swizzle (4000 = 8*500)
  int tm = wgid & 15, tn = wgid >> 4;        // tm fast: consecutive wgids share B-panel
  int r0 = tm * 256, c0 = tn * 128;
  int wm = wave >> 1, wn = wave & 1;         // 4M x 2N

  auto STAGE = [&](int kt, int bi) {
    unsigned short* bufA = (unsigned short*)lds + bi * 24576;
    unsigned short* bufB = bufA + 16384;
    #pragma unroll
    for (int i = 0; i < 4; ++i) {
      int slot = i * 512 + tid;              // 0..2047
      int row = slot >> 3, sg = slot & 7;
      int kg = sg ^ (row & 7);               // inverse-swizzled source granule
      const unsigned short* ga = A + (size_t)(r0 + row) * 1024 + kt * 64 + kg * 8;
      load16_to_lds(ga, &bufA[(i * 512 + wave * 64) * 8]);
    }
    #pragma unroll
    for (int i = 0; i < 2; ++i) {
      int slot = i * 512 + tid;              // 0..1023
      int row = slot >> 3, sg = slot & 7;
      int kg = sg ^ (row & 7);
      const unsigned short* gb = B + (size_t)(c0 + row) * 1024 + kt * 64 + kg * 8;
      load16_to_lds(gb, &bufB[(i * 512 + wave * 64) * 8]);
    }
  };

  f32x4 zero = {0.f, 0.f, 0.f, 0.f};
  f32x4 acc[4][4];
  #pragma unroll
  for (int i = 0; i < 4; ++i)
    #pragma unroll
    for (int jx = 0; jx < 4; ++jx) acc[i][jx] = zero;

  STAGE(0, 0);
  STAGE(1, 1);
  __asm__ volatile("s_waitcnt vmcnt(6)\n\ts_barrier" ::: "memory");  // tile0 landed

  for (int kt = 0; kt < 16; ++kt) {
    int bi = kt % 3;
    const unsigned short* bufA = (const unsigned short*)lds + bi * 24576;
    const unsigned short* bufB = bufA + 16384;
    {
      int nkt = kt + 2;
      if (nkt > 15) nkt = 15;                // tail: dead re-stage into dead buffer
      STAGE(nkt, (kt + 2) % 3);
    }
    short8 af[4][2], bf[4][2];
    #pragma unroll
    for (int kkb = 0; kkb < 2; ++kkb) {
      int kbyte = kkb * 64 + (lane >> 4) * 16;
      #pragma unroll
      for (int i = 0; i < 4; ++i) {
        int rowa = wm * 64 + i * 16 + (lane & 15);
        af[i][kkb] = *(const short8*)((const char*)bufA + rowa * 128 + (kbyte ^ ((rowa & 7) << 4)));
        int rowb = wn * 64 + i * 16 + (lane & 15);
        bf[i][kkb] = *(const short8*)((const char*)bufB + rowb * 128 + (kbyte ^ ((rowb & 7) << 4)));
      }
    }
    __builtin_amdgcn_s_setprio(1);
    #pragma unroll
    for (int kkb = 0; kkb < 2; ++kkb)
      #pragma unroll
      for (int i = 0; i < 4; ++i)
        #pragma unroll
        for (int jx = 0; jx < 4; ++jx)
          acc[i][jx] = __builtin_amdgcn_mfma_f32_16x16x32_bf16(af[i][kkb], bf[jx][kkb], acc[i][jx], 0, 0, 0);
    __builtin_amdgcn_s_setprio(0);
    // counted wait: stage(kt+2)'s 6 loads may stay in flight; stage(kt+1) landed.
    __asm__ volatile("s_waitcnt vmcnt(6)\n\ts_barrier" ::: "memory");
  }

  int rbase = r0 + wm * 64 + (lane >> 4) * 4;
  int cbase = c0 + wn * 64 + (lane & 15);
  #pragma unroll
  for (int i = 0; i < 4; ++i)
    #pragma unroll
    for (int jx = 0; jx < 4; ++jx)
      #pragma unroll
      for (int q = 0; q < 4; ++q)
        C[(size_t)(rbase + i * 16 + q) * 32000 + cbase + jx * 16] = acc[i][jx][q];
}

// ---------- launch ----------
extern "C" void kernel_launch(void* const* d_in, const int* in_sizes, int n_in,
                              void* d_out, int out_size, void* d_ws, size_t ws_size,
                              hipStream_t stream) {
  const int* tok = (const int*)d_in[0];
  const float* emb = (const float*)d_in[1];
  const float* Wx = (const float*)d_in[2];
  const float* Wh = (const float*)d_in[3];
  const float* bias = (const float*)d_in[4];
  const float* lmW = (const float*)d_in[5];
  float* out = (float*)d_out;

  const size_t OFF_LMW = 0;                       // bf16 lm_W: 65,536,000
  const size_t OFF_XW = 65536000;                 // f32 xw:   16,777,216
  const size_t OFF_HALL = OFF_XW + 16777216;      // bf16 h_all: 8,388,608
  const size_t OFF_HCMB = OFF_HALL + 8388608;     // u64 hcomb: 2*16*1024*8 = 262,144
  const size_t NEED = OFF_HCMB + 262144;
  if (ws_size < NEED) {
    sentinel_kernel<<<1, 1, 0, stream>>>(out);
    return;
  }
  char* ws = (char*)d_ws;
  unsigned short* lmW_bf = (unsigned short*)(ws + OFF_LMW);
  float* xw = (float*)(ws + OFF_XW);
  unsigned short* h_all = (unsigned short*)(ws + OFF_HALL);
  unsigned long long* hcomb = (unsigned long long*)(ws + OFF_HCMB);

  // tags must restart at 0 EVERY call (graph replay!)
  hipMemsetAsync(ws + OFF_HCMB, 0, 262144, stream);
  cvt_kernel<<<2048, 256, 0, stream>>>(lmW, lmW_bf, 32000 * 1024 / 8);
  xw_kernel<<<1024, 256, 0, stream>>>(tok, emb, Wx, bias, xw);
  rec_kernel<<<256, 1024, 0, stream>>>(Wh, xw, tok, hcomb, h_all);
  gemm_kernel<<<4000, 512, 0, stream>>>(h_all, lmW_bf, out);
}

// Round 6
// 978.734 us; speedup vs baseline: 1.2385x; 1.2385x over previous
//
#include <hip/hip_runtime.h>

#define PAD_IDX 0

typedef __attribute__((ext_vector_type(8))) short short8;
typedef __attribute__((ext_vector_type(4))) float f32x4;

// ---------- helpers ----------
__device__ __forceinline__ unsigned short f32_to_bf16_rne(float f) {
  unsigned int u = __builtin_bit_cast(unsigned int, f);
  u += 0x7FFFu + ((u >> 16) & 1u);
  return (unsigned short)(u >> 16);
}

__device__ __forceinline__ void load16_to_lds(const void* g, void* lds) {
  __builtin_amdgcn_global_load_lds(
      (const __attribute__((address_space(1))) unsigned int*)g,
      (__attribute__((address_space(3))) unsigned int*)lds,
      16, 0, 0);
}

// ---------- kernel 0: sentinel (only if ws too small) ----------
__global__ void sentinel_kernel(float* out) { out[0] = 1.0e6f; }

// ---------- kernel 1: lm_W f32 -> bf16 ----------
__global__ __launch_bounds__(256) void cvt_kernel(const float* __restrict__ in,
                                                  unsigned short* __restrict__ out,
                                                  int n8) {
  int stride = gridDim.x * blockDim.x;
  for (int i = blockIdx.x * blockDim.x + threadIdx.x; i < n8; i += stride) {
    float4 a = ((const float4*)in)[2 * i];
    float4 b = ((const float4*)in)[2 * i + 1];
    ushort4 lo, hi;
    lo.x = f32_to_bf16_rne(a.x); lo.y = f32_to_bf16_rne(a.y);
    lo.z = f32_to_bf16_rne(a.z); lo.w = f32_to_bf16_rne(a.w);
    hi.x = f32_to_bf16_rne(b.x); hi.y = f32_to_bf16_rne(b.y);
    hi.z = f32_to_bf16_rne(b.z); hi.w = f32_to_bf16_rne(b.w);
    ((ushort4*)out)[2 * i] = lo;
    ((ushort4*)out)[2 * i + 1] = hi;
  }
}

// ---------- kernel 2: xw[r][j] = emb[tok[r]] . Wx[j] + bias[j]  (f32) ----------
__global__ __launch_bounds__(256) void xw_kernel(const int* __restrict__ tok,
                                                 const float* __restrict__ emb,
                                                 const float* __restrict__ Wx,
                                                 const float* __restrict__ bias,
                                                 float* __restrict__ xw) {
  __shared__ float At[32][68];  // [k][m], padded
  __shared__ float Bt[32][68];  // [k][n]
  __shared__ int stok[64];
  int tid = threadIdx.x;
  int tm = blockIdx.x & 63;
  int tn = blockIdx.x >> 6;
  int r0 = tm * 64, j0 = tn * 64;
  if (tid < 64) stok[tid] = tok[r0 + tid];
  int tx = tid & 15, ty = tid >> 4;
  float acc[4][4] = {};
  for (int kt = 0; kt < 512; kt += 32) {
    __syncthreads();
    #pragma unroll
    for (int ii = 0; ii < 2; ++ii) {
      int idx = tid * 2 + ii;
      int m = idx >> 3, fv = idx & 7;
      float4 va = *(const float4*)&emb[(size_t)stok[m] * 512 + kt + fv * 4];
      float4 vb = *(const float4*)&Wx[(size_t)(j0 + m) * 512 + kt + fv * 4];
      At[fv * 4 + 0][m] = va.x; At[fv * 4 + 1][m] = va.y;
      At[fv * 4 + 2][m] = va.z; At[fv * 4 + 3][m] = va.w;
      Bt[fv * 4 + 0][m] = vb.x; Bt[fv * 4 + 1][m] = vb.y;
      Bt[fv * 4 + 2][m] = vb.z; Bt[fv * 4 + 3][m] = vb.w;
    }
    __syncthreads();
    #pragma unroll
    for (int k = 0; k < 32; ++k) {
      float4 a4 = *(const float4*)&At[k][ty * 4];
      float4 b4 = *(const float4*)&Bt[k][tx * 4];
      float av[4] = {a4.x, a4.y, a4.z, a4.w};
      float bv[4] = {b4.x, b4.y, b4.z, b4.w};
      #pragma unroll
      for (int i = 0; i < 4; ++i)
        #pragma unroll
        for (int jj = 0; jj < 4; ++jj) acc[i][jj] = fmaf(av[i], bv[jj], acc[i][jj]);
    }
  }
  #pragma unroll
  for (int i = 0; i < 4; ++i) {
    size_t row = (size_t)(r0 + ty * 4 + i) * 1024 + j0 + tx * 4;
    #pragma unroll
    for (int jj = 0; jj < 4; ++jj)
      xw[row + jj] = acc[i][jj] + bias[j0 + tx * 4 + jj];
  }
}

// ---------- kernel 3: recurrence (EXACT R4 structure — proven 507 us) ----------
// 256 WGs x 1024 threads, 1 WG/CU. chain c = blk&15, wg g = blk>>4 owns rows
// g*64..+63. Thread (row=tid>>4, kk=tid&15): k-slice kk*64..+63, 16 named f32x4
// weights. Sync: FUSED data+tag u64 {tag, h_bits}; poll own slot WITH s_sleep
// (sleep-less poll floods the fabric: R5 regression +258us). Two barriers/step.
__global__ __launch_bounds__(1024, 4) void rec_kernel(const float* __restrict__ Wh,
                                                      const float* __restrict__ xw,
                                                      const int* __restrict__ tok,
                                                      unsigned long long* hcomb,  // [2][16][1024]
                                                      unsigned short* __restrict__ h_all) {
  int c = blockIdx.x & 15;
  int g = blockIdx.x >> 4;
  int tid = threadIdx.x;
  int kk = tid & 15;
  int j = g * 64 + (tid >> 4);   // this thread-group's output row

  const float* wb = Wh + (size_t)j * 1024 + kk * 64;
#define LDW(i) f32x4 w##i = *(const f32x4*)(wb + i * 4);
  LDW(0) LDW(1) LDW(2) LDW(3) LDW(4) LDW(5) LDW(6) LDW(7)
  LDW(8) LDW(9) LDW(10) LDW(11) LDW(12) LDW(13) LDW(14) LDW(15)
#undef LDW

  __shared__ float hs[16 * 68];  // 16 slices x 64 (+4 pad)
  int lidx = (tid >> 6) * 68 + (tid & 63);  // staging slot: h[tid] -> hs[lidx]
  unsigned long long* hc0 = hcomb + (size_t)c * 1024;
  unsigned long long* hc1 = hcomb + 16 * 1024 + (size_t)c * 1024;
  bool writer = (kk == 0);

  for (int t = 0; t < 256; ++t) {
    // prefetch (hides under the poll)
    float xv = 0.f;
    int tkn = 1;
    if (writer) {
      xv = xw[((size_t)c * 256 + t) * 1024 + j];
      tkn = tok[c * 256 + t];
    }
    // poll own slot: tag==t means step-t data present in the same 8B load
    unsigned long long* src = ((t & 1) ? hc1 : hc0) + tid;
    unsigned long long v;
    int guard = 0;
    do {
      v = __hip_atomic_load(src, __ATOMIC_RELAXED, __HIP_MEMORY_SCOPE_AGENT);
      if ((unsigned int)(v >> 32) == (unsigned int)t) break;
      __builtin_amdgcn_s_sleep(1);
    } while (++guard < (1 << 20));  // fail loud (absmax), not hung
    hs[lidx] = __builtin_bit_cast(float, (unsigned int)v);
    __asm__ volatile("s_waitcnt lgkmcnt(0)\n\ts_barrier" ::: "memory");  // no vmcnt drain

    const float* hp = hs + kk * 68;
    f32x4 a0 = {0.f, 0.f, 0.f, 0.f}, a1 = a0, a2 = a0, a3 = a0;
#define FMAI(i, acc) { f32x4 h4 = *(const f32x4*)(hp + i * 4); acc += w##i * h4; }
    FMAI(0, a0) FMAI(1, a1) FMAI(2, a2) FMAI(3, a3)
    FMAI(4, a0) FMAI(5, a1) FMAI(6, a2) FMAI(7, a3)
    FMAI(8, a0) FMAI(9, a1) FMAI(10, a2) FMAI(11, a3)
    FMAI(12, a0) FMAI(13, a1) FMAI(14, a2) FMAI(15, a3)
#undef FMAI
    f32x4 aa = (a0 + a1) + (a2 + a3);
    float s = (aa[0] + aa[1]) + (aa[2] + aa[3]);
    s += __shfl_xor(s, 1);
    s += __shfl_xor(s, 2);
    s += __shfl_xor(s, 4);
    s += __shfl_xor(s, 8);

    if (writer) {
      float hnew;
      if (tkn != PAD_IDX) {
        float pre = xv + s;
        float e = __builtin_amdgcn_exp2f(pre * 2.8853900817779268f);  // exp(2x)
        hnew = 1.0f - 2.0f / (e + 1.0f);                              // tanh(x)
      } else {
        hnew = hs[(j >> 6) * 68 + (j & 63)];  // keep old h at pad
      }
      unsigned long long pv =
          ((unsigned long long)(unsigned int)(t + 1) << 32) |
          (unsigned long long)__builtin_bit_cast(unsigned int, hnew);
      __hip_atomic_store((((t + 1) & 1) ? hc1 : hc0) + j, pv,
                         __ATOMIC_RELAXED, __HIP_MEMORY_SCOPE_AGENT);
      h_all[((size_t)c * 256 + t) * 1024 + j] = f32_to_bf16_rne(hnew);
    }
    __asm__ volatile("s_waitcnt lgkmcnt(0)\n\ts_barrier" ::: "memory");  // hs reuse guard
  }
}

// ---------- kernel 4: logits = h_all(bf16) @ lm_W(bf16)^T, f32 out ----------
// BM=256 BN=128 BK=64. 512 thr (8 waves, 4M x 2N; per-wave 64x64). 3 LDS buffers
// (144 KB), 3-tile-deep global_load_lds pipeline, ONE s_waitcnt vmcnt(6) + raw
// s_barrier per K-tile (counted vmcnt, never 0 in loop), setprio around MFMA.
// R6: final vmcnt(0) drain after loop — no DMA may land in reassigned LDS.
__global__ __launch_bounds__(512) void gemm_kernel(const unsigned short* __restrict__ A,
                                                   const unsigned short* __restrict__ B,
                                                   float* __restrict__ C) {
  __shared__ unsigned short lds[3 * 24576];  // 3 x (A:16384 + B:8192 shorts) = 144 KB
  int tid = threadIdx.x;
  int lane = tid & 63, wave = tid >> 6;
  int bid = blockIdx.x;
  int wgid = (bid & 7) * 500 + (bid >> 3);   // bijective XCD swizzle (4000 = 8*500)
  int tm = wgid & 15, tn = wgid >> 4;        // tm fast: consecutive wgids share B-panel
  int r0 = tm * 256, c0 = tn * 128;
  int wm = wave >> 1, wn = wave & 1;         // 4M x 2N

  auto STAGE = [&](int kt, int bi) {
    unsigned short* bufA = (unsigned short*)lds + bi * 24576;
    unsigned short* bufB = bufA + 16384;
    #pragma unroll
    for (int i = 0; i < 4; ++i) {
      int slot = i * 512 + tid;              // 0..2047
      int row = slot >> 3, sg = slot & 7;
      int kg = sg ^ (row & 7);               // inverse-swizzled source granule
      const unsigned short* ga = A + (size_t)(r0 + row) * 1024 + kt * 64 + kg * 8;
      load16_to_lds(ga, &bufA[(i * 512 + wave * 64) * 8]);
    }
    #pragma unroll
    for (int i = 0; i < 2; ++i) {
      int slot = i * 512 + tid;              // 0..1023
      int row = slot >> 3, sg = slot & 7;
      int kg = sg ^ (row & 7);
      const unsigned short* gb = B + (size_t)(c0 + row) * 1024 + kt * 64 + kg * 8;
      load16_to_lds(gb, &bufB[(i * 512 + wave * 64) * 8]);
    }
  };

  f32x4 zero = {0.f, 0.f, 0.f, 0.f};
  f32x4 acc[4][4];
  #pragma unroll
  for (int i = 0; i < 4; ++i)
    #pragma unroll
    for (int jx = 0; jx < 4; ++jx) acc[i][jx] = zero;

  STAGE(0, 0);
  STAGE(1, 1);
  __asm__ volatile("s_waitcnt vmcnt(6)\n\ts_barrier" ::: "memory");  // tile0 landed

  for (int kt = 0; kt < 16; ++kt) {
    int bi = kt % 3;
    const unsigned short* bufA = (const unsigned short*)lds + bi * 24576;
    const unsigned short* bufB = bufA + 16384;
    {
      int nkt = kt + 2;
      if (nkt > 15) nkt = 15;                // tail: dead re-stage (keeps vmcnt math)
      STAGE(nkt, (kt + 2) % 3);
    }
    short8 af[4][2], bf[4][2];
    #pragma unroll
    for (int kkb = 0; kkb < 2; ++kkb) {
      int kbyte = kkb * 64 + (lane >> 4) * 16;
      #pragma unroll
      for (int i = 0; i < 4; ++i) {
        int rowa = wm * 64 + i * 16 + (lane & 15);
        af[i][kkb] = *(const short8*)((const char*)bufA + rowa * 128 + (kbyte ^ ((rowa & 7) << 4)));
        int rowb = wn * 64 + i * 16 + (lane & 15);
        bf[i][kkb] = *(const short8*)((const char*)bufB + rowb * 128 + (kbyte ^ ((rowb & 7) << 4)));
      }
    }
    __builtin_amdgcn_s_setprio(1);
    #pragma unroll
    for (int kkb = 0; kkb < 2; ++kkb)
      #pragma unroll
      for (int i = 0; i < 4; ++i)
        #pragma unroll
        for (int jx = 0; jx < 4; ++jx)
          acc[i][jx] = __builtin_amdgcn_mfma_f32_16x16x32_bf16(af[i][kkb], bf[jx][kkb], acc[i][jx], 0, 0, 0);
    __builtin_amdgcn_s_setprio(0);
    // counted wait: stage(kt+2)'s 6 loads may stay in flight; stage(kt+1) landed.
    __asm__ volatile("s_waitcnt vmcnt(6)\n\ts_barrier" ::: "memory");
  }
  // drain ALL outstanding LDS-DMA before this WG can retire (LDS reassignment!)
  __asm__ volatile("s_waitcnt vmcnt(0)" ::: "memory");

  int rbase = r0 + wm * 64 + (lane >> 4) * 4;
  int cbase = c0 + wn * 64 + (lane & 15);
  #pragma unroll
  for (int i = 0; i < 4; ++i)
    #pragma unroll
    for (int jx = 0; jx < 4; ++jx)
      #pragma unroll
      for (int q = 0; q < 4; ++q)
        C[(size_t)(rbase + i * 16 + q) * 32000 + cbase + jx * 16] = acc[i][jx][q];
}

// ---------- launch ----------
extern "C" void kernel_launch(void* const* d_in, const int* in_sizes, int n_in,
                              void* d_out, int out_size, void* d_ws, size_t ws_size,
                              hipStream_t stream) {
  const int* tok = (const int*)d_in[0];
  const float* emb = (const float*)d_in[1];
  const float* Wx = (const float*)d_in[2];
  const float* Wh = (const float*)d_in[3];
  const float* bias = (const float*)d_in[4];
  const float* lmW = (const float*)d_in[5];
  float* out = (float*)d_out;

  const size_t OFF_LMW = 0;                       // bf16 lm_W: 65,536,000
  const size_t OFF_XW = 65536000;                 // f32 xw:   16,777,216
  const size_t OFF_HALL = OFF_XW + 16777216;      // bf16 h_all: 8,388,608
  const size_t OFF_HCMB = OFF_HALL + 8388608;     // u64 hcomb: 2*16*1024*8 = 262,144
  const size_t NEED = OFF_HCMB + 262144;
  if (ws_size < NEED) {
    sentinel_kernel<<<1, 1, 0, stream>>>(out);
    return;
  }
  char* ws = (char*)d_ws;
  unsigned short* lmW_bf = (unsigned short*)(ws + OFF_LMW);
  float* xw = (float*)(ws + OFF_XW);
  unsigned short* h_all = (unsigned short*)(ws + OFF_HALL);
  unsigned long long* hcomb = (unsigned long long*)(ws + OFF_HCMB);

  // tags must restart at 0 EVERY call (graph replay!)
  hipMemsetAsync(ws + OFF_HCMB, 0, 262144, stream);
  cvt_kernel<<<2048, 256, 0, stream>>>(lmW, lmW_bf, 32000 * 1024 / 8);
  xw_kernel<<<1024, 256, 0, stream>>>(tok, emb, Wx, bias, xw);
  rec_kernel<<<256, 1024, 0, stream>>>(Wh, xw, tok, hcomb, h_all);
  gemm_kernel<<<4000, 512, 0, stream>>>(h_all, lmW_bf, out);
}

// Round 7
// 912.755 us; speedup vs baseline: 1.3280x; 1.0723x over previous
//
#include <hip/hip_runtime.h>

#define PAD_IDX 0

typedef __attribute__((ext_vector_type(8))) short short8;
typedef __attribute__((ext_vector_type(4))) float f32x4;

// ---------- helpers ----------
__device__ __forceinline__ unsigned short f32_to_bf16_rne(float f) {
  unsigned int u = __builtin_bit_cast(unsigned int, f);
  u += 0x7FFFu + ((u >> 16) & 1u);
  return (unsigned short)(u >> 16);
}

__device__ __forceinline__ void load16_to_lds(const void* g, void* lds) {
  __builtin_amdgcn_global_load_lds(
      (const __attribute__((address_space(1))) unsigned int*)g,
      (__attribute__((address_space(3))) unsigned int*)lds,
      16, 0, 0);
}

// ---------- kernel 0: sentinel (only if ws too small) ----------
__global__ void sentinel_kernel(float* out) { out[0] = 1.0e6f; }

// ---------- kernel 1: lm_W f32 -> bf16 ----------
__global__ __launch_bounds__(256) void cvt_kernel(const float* __restrict__ in,
                                                  unsigned short* __restrict__ out,
                                                  int n8) {
  int stride = gridDim.x * blockDim.x;
  for (int i = blockIdx.x * blockDim.x + threadIdx.x; i < n8; i += stride) {
    float4 a = ((const float4*)in)[2 * i];
    float4 b = ((const float4*)in)[2 * i + 1];
    ushort4 lo, hi;
    lo.x = f32_to_bf16_rne(a.x); lo.y = f32_to_bf16_rne(a.y);
    lo.z = f32_to_bf16_rne(a.z); lo.w = f32_to_bf16_rne(a.w);
    hi.x = f32_to_bf16_rne(b.x); hi.y = f32_to_bf16_rne(b.y);
    hi.z = f32_to_bf16_rne(b.z); hi.w = f32_to_bf16_rne(b.w);
    ((ushort4*)out)[2 * i] = lo;
    ((ushort4*)out)[2 * i + 1] = hi;
  }
}

// ---------- kernel 2: xw[r][j] = emb[tok[r]] . Wx[j] + bias[j]  (f32) ----------
__global__ __launch_bounds__(256) void xw_kernel(const int* __restrict__ tok,
                                                 const float* __restrict__ emb,
                                                 const float* __restrict__ Wx,
                                                 const float* __restrict__ bias,
                                                 float* __restrict__ xw) {
  __shared__ float At[32][68];  // [k][m], padded
  __shared__ float Bt[32][68];  // [k][n]
  __shared__ int stok[64];
  int tid = threadIdx.x;
  int tm = blockIdx.x & 63;
  int tn = blockIdx.x >> 6;
  int r0 = tm * 64, j0 = tn * 64;
  if (tid < 64) stok[tid] = tok[r0 + tid];
  int tx = tid & 15, ty = tid >> 4;
  float acc[4][4] = {};
  for (int kt = 0; kt < 512; kt += 32) {
    __syncthreads();
    #pragma unroll
    for (int ii = 0; ii < 2; ++ii) {
      int idx = tid * 2 + ii;
      int m = idx >> 3, fv = idx & 7;
      float4 va = *(const float4*)&emb[(size_t)stok[m] * 512 + kt + fv * 4];
      float4 vb = *(const float4*)&Wx[(size_t)(j0 + m) * 512 + kt + fv * 4];
      At[fv * 4 + 0][m] = va.x; At[fv * 4 + 1][m] = va.y;
      At[fv * 4 + 2][m] = va.z; At[fv * 4 + 3][m] = va.w;
      Bt[fv * 4 + 0][m] = vb.x; Bt[fv * 4 + 1][m] = vb.y;
      Bt[fv * 4 + 2][m] = vb.z; Bt[fv * 4 + 3][m] = vb.w;
    }
    __syncthreads();
    #pragma unroll
    for (int k = 0; k < 32; ++k) {
      float4 a4 = *(const float4*)&At[k][ty * 4];
      float4 b4 = *(const float4*)&Bt[k][tx * 4];
      float av[4] = {a4.x, a4.y, a4.z, a4.w};
      float bv[4] = {b4.x, b4.y, b4.z, b4.w};
      #pragma unroll
      for (int i = 0; i < 4; ++i)
        #pragma unroll
        for (int jj = 0; jj < 4; ++jj) acc[i][jj] = fmaf(av[i], bv[jj], acc[i][jj]);
    }
  }
  #pragma unroll
  for (int i = 0; i < 4; ++i) {
    size_t row = (size_t)(r0 + ty * 4 + i) * 1024 + j0 + tx * 4;
    #pragma unroll
    for (int jj = 0; jj < 4; ++jj)
      xw[row + jj] = acc[i][jj] + bias[j0 + tx * 4 + jj];
  }
}

// ---------- kernel 3: recurrence (R6 structure + VGPR weight pin) ----------
// 256 WGs x 1024 threads, 1 WG/CU. chain c = blk&15, wg g = blk>>4 owns rows
// g*64..+63. Thread (row=tid>>4, kk=tid&15): k-slice kk*64..+63, 16 named f32x4
// weights. R6 bug (counters): VGPR_Count=56 < 64 weight regs -> compiler remats
// weights from L2 EVERY step = 8MB/XCD/step at L2 BW = the whole 2us/step.
// Fix: asm "+v" pin inside the loop forces register residency (rule-17 trick).
__global__ __launch_bounds__(1024, 4) void rec_kernel(const float* __restrict__ Wh,
                                                      const float* __restrict__ xw,
                                                      const int* __restrict__ tok,
                                                      unsigned long long* hcomb,  // [2][16][1024]
                                                      unsigned short* __restrict__ h_all) {
  int c = blockIdx.x & 15;
  int g = blockIdx.x >> 4;
  int tid = threadIdx.x;
  int kk = tid & 15;
  int j = g * 64 + (tid >> 4);   // this thread-group's output row

  const float* wb = Wh + (size_t)j * 1024 + kk * 64;
#define LDW(i) f32x4 w##i = *(const f32x4*)(wb + i * 4);
  LDW(0) LDW(1) LDW(2) LDW(3) LDW(4) LDW(5) LDW(6) LDW(7)
  LDW(8) LDW(9) LDW(10) LDW(11) LDW(12) LDW(13) LDW(14) LDW(15)
#undef LDW

  __shared__ float hs[16 * 68];  // 16 slices x 64 (+4 pad)
  int lidx = (tid >> 6) * 68 + (tid & 63);  // staging slot: h[tid] -> hs[lidx]
  unsigned long long* hc0 = hcomb + (size_t)c * 1024;
  unsigned long long* hc1 = hcomb + 16 * 1024 + (size_t)c * 1024;
  bool writer = (kk == 0);

  for (int t = 0; t < 256; ++t) {
    // PIN: weights must stay materialized in VGPRs across the loop.
    asm volatile("" : "+v"(w0), "+v"(w1), "+v"(w2), "+v"(w3),
                      "+v"(w4), "+v"(w5), "+v"(w6), "+v"(w7),
                      "+v"(w8), "+v"(w9), "+v"(w10), "+v"(w11),
                      "+v"(w12), "+v"(w13), "+v"(w14), "+v"(w15));
    // prefetch (hides under the poll)
    float xv = 0.f;
    int tkn = 1;
    if (writer) {
      xv = xw[((size_t)c * 256 + t) * 1024 + j];
      tkn = tok[c * 256 + t];
    }
    // poll own slot: tag==t means step-t data present in the same 8B load
    unsigned long long* src = ((t & 1) ? hc1 : hc0) + tid;
    unsigned long long v;
    int guard = 0;
    do {
      v = __hip_atomic_load(src, __ATOMIC_RELAXED, __HIP_MEMORY_SCOPE_AGENT);
      if ((unsigned int)(v >> 32) == (unsigned int)t) break;
      __builtin_amdgcn_s_sleep(1);
    } while (++guard < (1 << 20));  // fail loud (absmax), not hung
    hs[lidx] = __builtin_bit_cast(float, (unsigned int)v);
    __asm__ volatile("s_waitcnt lgkmcnt(0)\n\ts_barrier" ::: "memory");  // no vmcnt drain

    const float* hp = hs + kk * 68;
    f32x4 a0 = {0.f, 0.f, 0.f, 0.f}, a1 = a0, a2 = a0, a3 = a0;
#define FMAI(i, acc) { f32x4 h4 = *(const f32x4*)(hp + i * 4); acc += w##i * h4; }
    FMAI(0, a0) FMAI(1, a1) FMAI(2, a2) FMAI(3, a3)
    FMAI(4, a0) FMAI(5, a1) FMAI(6, a2) FMAI(7, a3)
    FMAI(8, a0) FMAI(9, a1) FMAI(10, a2) FMAI(11, a3)
    FMAI(12, a0) FMAI(13, a1) FMAI(14, a2) FMAI(15, a3)
#undef FMAI
    f32x4 aa = (a0 + a1) + (a2 + a3);
    float s = (aa[0] + aa[1]) + (aa[2] + aa[3]);
    s += __shfl_xor(s, 1);
    s += __shfl_xor(s, 2);
    s += __shfl_xor(s, 4);
    s += __shfl_xor(s, 8);

    if (writer) {
      float hnew;
      if (tkn != PAD_IDX) {
        float pre = xv + s;
        float e = __builtin_amdgcn_exp2f(pre * 2.8853900817779268f);  // exp(2x)
        hnew = 1.0f - 2.0f / (e + 1.0f);                              // tanh(x)
      } else {
        hnew = hs[(j >> 6) * 68 + (j & 63)];  // keep old h at pad
      }
      unsigned long long pv =
          ((unsigned long long)(unsigned int)(t + 1) << 32) |
          (unsigned long long)__builtin_bit_cast(unsigned int, hnew);
      __hip_atomic_store((((t + 1) & 1) ? hc1 : hc0) + j, pv,
                         __ATOMIC_RELAXED, __HIP_MEMORY_SCOPE_AGENT);
      h_all[((size_t)c * 256 + t) * 1024 + j] = f32_to_bf16_rne(hnew);
    }
    __asm__ volatile("s_waitcnt lgkmcnt(0)\n\ts_barrier" ::: "memory");  // hs reuse guard
  }
}

// ---------- kernel 4: logits = h_all(bf16) @ lm_W(bf16)^T, f32 out ----------
// R7: BM=256 BN=256 BK=64, 512 thr (8 waves 2Mx4N; per-wave 128x64, 64 MFMA/tile).
// 2 LDS stages (128 KB), counted vmcnt(8). Per K-tile: ds_read 24 frags ->
// lgkmcnt(0) -> barrier (all waves' reads retired) -> restage this buffer for
// kt+2 -> 64 MFMA (setprio) -> vmcnt(8) (kt+1 landed) -> barrier. Dead-stage on
// tail keeps vmcnt math constant; final vmcnt(0) drain before retire.
__global__ __launch_bounds__(512) void gemm_kernel(const unsigned short* __restrict__ A,
                                                   const unsigned short* __restrict__ B,
                                                   float* __restrict__ C) {
  __shared__ unsigned short lds[2 * 32768];  // 2 x (A:16384 + B:16384 shorts) = 128 KB
  int tid = threadIdx.x;
  int lane = tid & 63, wave = tid >> 6;
  int bid = blockIdx.x;
  int wgid = (bid & 7) * 250 + (bid >> 3);   // bijective XCD swizzle (2000 = 8*250)
  int tm = wgid & 15, tn = wgid >> 4;        // tm fast: consecutive wgids share B panel
  int r0 = tm * 256, c0 = tn * 256;
  int wm = wave >> 2, wn = wave & 3;         // 2M x 4N

  auto STAGE = [&](int kt, int st) {
    unsigned short* bufA = (unsigned short*)lds + st * 32768;
    unsigned short* bufB = bufA + 16384;
    #pragma unroll
    for (int i = 0; i < 4; ++i) {
      int slot = i * 512 + tid;              // 0..2047 = 256 rows x 8 granules
      int row = slot >> 3, sg = slot & 7;
      int kg = sg ^ (row & 7);               // inverse-swizzled source granule
      const unsigned short* ga = A + (size_t)(r0 + row) * 1024 + kt * 64 + kg * 8;
      load16_to_lds(ga, &bufA[(i * 512 + wave * 64) * 8]);
    }
    #pragma unroll
    for (int i = 0; i < 4; ++i) {
      int slot = i * 512 + tid;
      int row = slot >> 3, sg = slot & 7;
      int kg = sg ^ (row & 7);
      const unsigned short* gb = B + (size_t)(c0 + row) * 1024 + kt * 64 + kg * 8;
      load16_to_lds(gb, &bufB[(i * 512 + wave * 64) * 8]);
    }
  };

  f32x4 zero = {0.f, 0.f, 0.f, 0.f};
  f32x4 acc[8][4];
  #pragma unroll
  for (int i = 0; i < 8; ++i)
    #pragma unroll
    for (int jx = 0; jx < 4; ++jx) acc[i][jx] = zero;

  STAGE(0, 0);
  STAGE(1, 1);
  __asm__ volatile("s_waitcnt vmcnt(8)\n\ts_barrier" ::: "memory");  // tile0 landed

  for (int kt = 0; kt < 16; ++kt) {
    int st = kt & 1;
    const unsigned short* bufA = (const unsigned short*)lds + st * 32768;
    const unsigned short* bufB = bufA + 16384;

    short8 af[8][2], bf[4][2];
    #pragma unroll
    for (int kkb = 0; kkb < 2; ++kkb) {
      int kbyte = kkb * 64 + (lane >> 4) * 16;
      #pragma unroll
      for (int i = 0; i < 8; ++i) {
        int rowa = wm * 128 + i * 16 + (lane & 15);
        af[i][kkb] = *(const short8*)((const char*)bufA + rowa * 128 + (kbyte ^ ((rowa & 7) << 4)));
      }
      #pragma unroll
      for (int i = 0; i < 4; ++i) {
        int rowb = wn * 64 + i * 16 + (lane & 15);
        bf[i][kkb] = *(const short8*)((const char*)bufB + rowb * 128 + (kbyte ^ ((rowb & 7) << 4)));
      }
    }
    // all waves' ds_reads of this buffer must retire before restaging into it
    __asm__ volatile("s_waitcnt lgkmcnt(0)\n\ts_barrier" ::: "memory");
    {
      int nkt = kt + 2;
      if (nkt > 15) nkt = 15;                // tail: dead re-stage (keeps vmcnt math)
      STAGE(nkt, st);
    }
    __builtin_amdgcn_s_setprio(1);
    #pragma unroll
    for (int kkb = 0; kkb < 2; ++kkb)
      #pragma unroll
      for (int i = 0; i < 8; ++i)
        #pragma unroll
        for (int jx = 0; jx < 4; ++jx)
          acc[i][jx] = __builtin_amdgcn_mfma_f32_16x16x32_bf16(af[i][kkb], bf[jx][kkb], acc[i][jx], 0, 0, 0);
    __builtin_amdgcn_s_setprio(0);
    // stage(kt+1) (8 older loads) landed; stage(kt+2)'s 8 may stay in flight
    __asm__ volatile("s_waitcnt vmcnt(8)\n\ts_barrier" ::: "memory");
  }
  // drain ALL outstanding LDS-DMA before this WG can retire (LDS reassignment!)
  __asm__ volatile("s_waitcnt vmcnt(0)" ::: "memory");

  int rbase = r0 + wm * 128 + (lane >> 4) * 4;
  int cbase = c0 + wn * 64 + (lane & 15);
  #pragma unroll
  for (int i = 0; i < 8; ++i)
    #pragma unroll
    for (int jx = 0; jx < 4; ++jx)
      #pragma unroll
      for (int q = 0; q < 4; ++q)
        C[(size_t)(rbase + i * 16 + q) * 32000 + cbase + jx * 16] = acc[i][jx][q];
}

// ---------- launch ----------
extern "C" void kernel_launch(void* const* d_in, const int* in_sizes, int n_in,
                              void* d_out, int out_size, void* d_ws, size_t ws_size,
                              hipStream_t stream) {
  const int* tok = (const int*)d_in[0];
  const float* emb = (const float*)d_in[1];
  const float* Wx = (const float*)d_in[2];
  const float* Wh = (const float*)d_in[3];
  const float* bias = (const float*)d_in[4];
  const float* lmW = (const float*)d_in[5];
  float* out = (float*)d_out;

  const size_t OFF_LMW = 0;                       // bf16 lm_W: 65,536,000
  const size_t OFF_XW = 65536000;                 // f32 xw:   16,777,216
  const size_t OFF_HALL = OFF_XW + 16777216;      // bf16 h_all: 8,388,608
  const size_t OFF_HCMB = OFF_HALL + 8388608;     // u64 hcomb: 2*16*1024*8 = 262,144
  const size_t NEED = OFF_HCMB + 262144;
  if (ws_size < NEED) {
    sentinel_kernel<<<1, 1, 0, stream>>>(out);
    return;
  }
  char* ws = (char*)d_ws;
  unsigned short* lmW_bf = (unsigned short*)(ws + OFF_LMW);
  float* xw = (float*)(ws + OFF_XW);
  unsigned short* h_all = (unsigned short*)(ws + OFF_HALL);
  unsigned long long* hcomb = (unsigned long long*)(ws + OFF_HCMB);

  // tags must restart at 0 EVERY call (graph replay!)
  hipMemsetAsync(ws + OFF_HCMB, 0, 262144, stream);
  cvt_kernel<<<2048, 256, 0, stream>>>(lmW, lmW_bf, 32000 * 1024 / 8);
  xw_kernel<<<1024, 256, 0, stream>>>(tok, emb, Wx, bias, xw);
  rec_kernel<<<256, 1024, 0, stream>>>(Wh, xw, tok, hcomb, h_all);
  gemm_kernel<<<2000, 512, 0, stream>>>(h_all, lmW_bf, out);
}

// Round 8
// 873.870 us; speedup vs baseline: 1.3871x; 1.0445x over previous
//
#include <hip/hip_runtime.h>

#define PAD_IDX 0

typedef __attribute__((ext_vector_type(8))) short short8;
typedef __attribute__((ext_vector_type(4))) float f32x4;

// ---------- helpers ----------
__device__ __forceinline__ unsigned short f32_to_bf16_rne(float f) {
  unsigned int u = __builtin_bit_cast(unsigned int, f);
  u += 0x7FFFu + ((u >> 16) & 1u);
  return (unsigned short)(u >> 16);
}

__device__ __forceinline__ void load16_to_lds(const void* g, void* lds) {
  __builtin_amdgcn_global_load_lds(
      (const __attribute__((address_space(1))) unsigned int*)g,
      (__attribute__((address_space(3))) unsigned int*)lds,
      16, 0, 0);
}

// ---------- kernel 0: sentinel (only if ws too small) ----------
__global__ void sentinel_kernel(float* out) { out[0] = 1.0e6f; }

// ---------- kernel 1: merged xw + cvt (role by blockIdx) ----------
// blocks 0..1023: xw[r][j] = emb[tok[r]] . Wx[j] + bias[j] (f32, 64x64 tiles)
// blocks 1024..1535: lm_W f32 -> bf16 grid-stride (BW-bound, overlaps xw compute)
__global__ __launch_bounds__(256) void xwcvt_kernel(const int* __restrict__ tok,
                                                    const float* __restrict__ emb,
                                                    const float* __restrict__ Wx,
                                                    const float* __restrict__ bias,
                                                    float* __restrict__ xw,
                                                    const float* __restrict__ lmW,
                                                    unsigned short* __restrict__ lmW_bf) {
  int tid = threadIdx.x;
  if (blockIdx.x >= 1024) {
    const int n8 = 32000 * 1024 / 8;
    int stride = 512 * 256;
    for (int i = (blockIdx.x - 1024) * 256 + tid; i < n8; i += stride) {
      float4 a = ((const float4*)lmW)[2 * i];
      float4 b = ((const float4*)lmW)[2 * i + 1];
      ushort4 lo, hi;
      lo.x = f32_to_bf16_rne(a.x); lo.y = f32_to_bf16_rne(a.y);
      lo.z = f32_to_bf16_rne(a.z); lo.w = f32_to_bf16_rne(a.w);
      hi.x = f32_to_bf16_rne(b.x); hi.y = f32_to_bf16_rne(b.y);
      hi.z = f32_to_bf16_rne(b.z); hi.w = f32_to_bf16_rne(b.w);
      ((ushort4*)lmW_bf)[2 * i] = lo;
      ((ushort4*)lmW_bf)[2 * i + 1] = hi;
    }
    return;
  }
  __shared__ float At[32][68];  // [k][m], padded
  __shared__ float Bt[32][68];  // [k][n]
  __shared__ int stok[64];
  int tm = blockIdx.x & 63;
  int tn = blockIdx.x >> 6;
  int r0 = tm * 64, j0 = tn * 64;
  if (tid < 64) stok[tid] = tok[r0 + tid];
  int tx = tid & 15, ty = tid >> 4;
  float acc[4][4] = {};
  for (int kt = 0; kt < 512; kt += 32) {
    __syncthreads();
    #pragma unroll
    for (int ii = 0; ii < 2; ++ii) {
      int idx = tid * 2 + ii;
      int m = idx >> 3, fv = idx & 7;
      float4 va = *(const float4*)&emb[(size_t)stok[m] * 512 + kt + fv * 4];
      float4 vb = *(const float4*)&Wx[(size_t)(j0 + m) * 512 + kt + fv * 4];
      At[fv * 4 + 0][m] = va.x; At[fv * 4 + 1][m] = va.y;
      At[fv * 4 + 2][m] = va.z; At[fv * 4 + 3][m] = va.w;
      Bt[fv * 4 + 0][m] = vb.x; Bt[fv * 4 + 1][m] = vb.y;
      Bt[fv * 4 + 2][m] = vb.z; Bt[fv * 4 + 3][m] = vb.w;
    }
    __syncthreads();
    #pragma unroll
    for (int k = 0; k < 32; ++k) {
      float4 a4 = *(const float4*)&At[k][ty * 4];
      float4 b4 = *(const float4*)&Bt[k][tx * 4];
      float av[4] = {a4.x, a4.y, a4.z, a4.w};
      float bv[4] = {b4.x, b4.y, b4.z, b4.w};
      #pragma unroll
      for (int i = 0; i < 4; ++i)
        #pragma unroll
        for (int jj = 0; jj < 4; ++jj) acc[i][jj] = fmaf(av[i], bv[jj], acc[i][jj]);
    }
  }
  #pragma unroll
  for (int i = 0; i < 4; ++i) {
    size_t row = (size_t)(r0 + ty * 4 + i) * 1024 + j0 + tx * 4;
    #pragma unroll
    for (int jj = 0; jj < 4; ++jj)
      xw[row + jj] = acc[i][jj] + bias[j0 + tx * 4 + jj];
  }
}

// ---------- kernel 3: recurrence (R8: wave-autonomous k-slices) ----------
// 256 WGs x 1024 threads. chain c = blk&15 (XCD-local under round-robin),
// wg g = blk>>4 owns rows g*64..+63. Wave w owns k-slice [w*64,w*64+64);
// lane l computes the FULL 64-wide partial for row g*64+l (16 named f32x4 =
// 64 weight regs). Poll+stage+FMA is wave-autonomous (no barrier): ds_write ->
// lgkmcnt(0) -> broadcast ds_reads. ONE barrier/step before wave-0's pbuf
// reduce. Race audit: all waves' step-(t+1) hs/pbuf writes are gated on
// wave-0's step-t hcomb store (poll), which follows its hs/pbuf reads.
__global__ __launch_bounds__(1024, 4) void rec_kernel(const float* __restrict__ Wh,
                                                      const float* __restrict__ xw,
                                                      const int* __restrict__ tok,
                                                      unsigned long long* hcomb,  // [2][16][1024]
                                                      unsigned short* __restrict__ h_all) {
  int c = blockIdx.x & 15;
  int g = blockIdx.x >> 4;
  int tid = threadIdx.x;
  int w = tid >> 6;              // wave = k-slice index
  int l = tid & 63;              // lane = row within group (and poll index)
  int j = g * 64 + l;            // output row this lane computes

  const float* wb = Wh + (size_t)j * 1024 + w * 64;
#define LDW(i) f32x4 w##i = *(const f32x4*)(wb + i * 4);
  LDW(0) LDW(1) LDW(2) LDW(3) LDW(4) LDW(5) LDW(6) LDW(7)
  LDW(8) LDW(9) LDW(10) LDW(11) LDW(12) LDW(13) LDW(14) LDW(15)
#undef LDW

  __shared__ float hs[16][64];    // [slice][k-within-slice]
  __shared__ float pbuf[16][64];  // [slice][row] partial sums
  unsigned long long* hc0 = hcomb + (size_t)c * 1024;
  unsigned long long* hc1 = hcomb + 16 * 1024 + (size_t)c * 1024;
  bool writer = (w == 0);

  for (int t = 0; t < 256; ++t) {
    // writer prefetch (hides under the poll)
    float xv = 0.f;
    int tkn = 1;
    if (writer) {
      xv = xw[((size_t)c * 256 + t) * 1024 + j];
      tkn = tok[c * 256 + t];
    }
    // poll own slot (slot tid = h[w*64+l]): tag==t means data in the same 8B
    unsigned long long* src = ((t & 1) ? hc1 : hc0) + tid;
    unsigned long long v;
    int guard = 0;
    do {
      v = __hip_atomic_load(src, __ATOMIC_RELAXED, __HIP_MEMORY_SCOPE_AGENT);
      if ((unsigned int)(v >> 32) == (unsigned int)t) break;
      __builtin_amdgcn_s_sleep(1);
    } while (++guard < (1 << 20));  // fail loud (absmax), not hung
    hs[w][l] = __builtin_bit_cast(float, (unsigned int)v);
    // wave-local share: all 64 lanes' ds_writes complete at lgkmcnt(0); no barrier
    __asm__ volatile("s_waitcnt lgkmcnt(0)" ::: "memory");

    const float* hp = &hs[w][0];   // broadcast reads (same addr all lanes: free)
    f32x4 a0 = {0.f, 0.f, 0.f, 0.f}, a1 = a0, a2 = a0, a3 = a0;
#define FMAI(i, acc) { f32x4 h4 = *(const f32x4*)(hp + i * 4); acc += w##i * h4; }
    FMAI(0, a0) FMAI(1, a1) FMAI(2, a2) FMAI(3, a3)
    FMAI(4, a0) FMAI(5, a1) FMAI(6, a2) FMAI(7, a3)
    FMAI(8, a0) FMAI(9, a1) FMAI(10, a2) FMAI(11, a3)
    FMAI(12, a0) FMAI(13, a1) FMAI(14, a2) FMAI(15, a3)
#undef FMAI
    f32x4 aa = (a0 + a1) + (a2 + a3);
    pbuf[w][l] = (aa[0] + aa[1]) + (aa[2] + aa[3]);
    __asm__ volatile("s_waitcnt lgkmcnt(0)\n\ts_barrier" ::: "memory");

    if (writer) {
      float s = 0.f;
      #pragma unroll
      for (int q = 0; q < 16; ++q) s += pbuf[q][l];  // lanes stride 4B: 2-way, free
      float hnew;
      if (tkn != PAD_IDX) {
        float pre = xv + s;
        float e = __builtin_amdgcn_exp2f(pre * 2.8853900817779268f);  // exp(2x)
        hnew = 1.0f - 2.0f / (e + 1.0f);                              // tanh(x)
      } else {
        hnew = hs[g][l];  // old h of own row (slice g holds h[g*64..+63])
      }
      unsigned long long pv =
          ((unsigned long long)(unsigned int)(t + 1) << 32) |
          (unsigned long long)__builtin_bit_cast(unsigned int, hnew);
      __hip_atomic_store((((t + 1) & 1) ? hc1 : hc0) + j, pv,
                         __ATOMIC_RELAXED, __HIP_MEMORY_SCOPE_AGENT);
      h_all[((size_t)c * 256 + t) * 1024 + j] = f32_to_bf16_rne(hnew);
    }
  }
}

// ---------- kernel 4: logits = h_all(bf16) @ lm_W(bf16)^T, f32 out ----------
// BM=256 BN=256 BK=64, 512 thr (8 waves 2Mx4N; per-wave 128x64, 64 MFMA/tile).
// 2 LDS stages (128 KB), counted vmcnt(8). Final vmcnt(0) drain before retire.
__global__ __launch_bounds__(512) void gemm_kernel(const unsigned short* __restrict__ A,
                                                   const unsigned short* __restrict__ B,
                                                   float* __restrict__ C) {
  __shared__ unsigned short lds[2 * 32768];  // 2 x (A:16384 + B:16384 shorts) = 128 KB
  int tid = threadIdx.x;
  int lane = tid & 63, wave = tid >> 6;
  int bid = blockIdx.x;
  int wgid = (bid & 7) * 250 + (bid >> 3);   // bijective XCD swizzle (2000 = 8*250)
  int tm = wgid & 15, tn = wgid >> 4;        // tm fast: consecutive wgids share B panel
  int r0 = tm * 256, c0 = tn * 256;
  int wm = wave >> 2, wn = wave & 3;         // 2M x 4N

  auto STAGE = [&](int kt, int st) {
    unsigned short* bufA = (unsigned short*)lds + st * 32768;
    unsigned short* bufB = bufA + 16384;
    #pragma unroll
    for (int i = 0; i < 4; ++i) {
      int slot = i * 512 + tid;              // 0..2047 = 256 rows x 8 granules
      int row = slot >> 3, sg = slot & 7;
      int kg = sg ^ (row & 7);               // inverse-swizzled source granule
      const unsigned short* ga = A + (size_t)(r0 + row) * 1024 + kt * 64 + kg * 8;
      load16_to_lds(ga, &bufA[(i * 512 + wave * 64) * 8]);
    }
    #pragma unroll
    for (int i = 0; i < 4; ++i) {
      int slot = i * 512 + tid;
      int row = slot >> 3, sg = slot & 7;
      int kg = sg ^ (row & 7);
      const unsigned short* gb = B + (size_t)(c0 + row) * 1024 + kt * 64 + kg * 8;
      load16_to_lds(gb, &bufB[(i * 512 + wave * 64) * 8]);
    }
  };

  f32x4 zero = {0.f, 0.f, 0.f, 0.f};
  f32x4 acc[8][4];
  #pragma unroll
  for (int i = 0; i < 8; ++i)
    #pragma unroll
    for (int jx = 0; jx < 4; ++jx) acc[i][jx] = zero;

  STAGE(0, 0);
  STAGE(1, 1);
  __asm__ volatile("s_waitcnt vmcnt(8)\n\ts_barrier" ::: "memory");  // tile0 landed

  for (int kt = 0; kt < 16; ++kt) {
    int st = kt & 1;
    const unsigned short* bufA = (const unsigned short*)lds + st * 32768;
    const unsigned short* bufB = bufA + 16384;

    short8 af[8][2], bf[4][2];
    #pragma unroll
    for (int kkb = 0; kkb < 2; ++kkb) {
      int kbyte = kkb * 64 + (lane >> 4) * 16;
      #pragma unroll
      for (int i = 0; i < 8; ++i) {
        int rowa = wm * 128 + i * 16 + (lane & 15);
        af[i][kkb] = *(const short8*)((const char*)bufA + rowa * 128 + (kbyte ^ ((rowa & 7) << 4)));
      }
      #pragma unroll
      for (int i = 0; i < 4; ++i) {
        int rowb = wn * 64 + i * 16 + (lane & 15);
        bf[i][kkb] = *(const short8*)((const char*)bufB + rowb * 128 + (kbyte ^ ((rowb & 7) << 4)));
      }
    }
    // all waves' ds_reads of this buffer must retire before restaging into it
    __asm__ volatile("s_waitcnt lgkmcnt(0)\n\ts_barrier" ::: "memory");
    {
      int nkt = kt + 2;
      if (nkt > 15) nkt = 15;                // tail: dead re-stage (keeps vmcnt math)
      STAGE(nkt, st);
    }
    __builtin_amdgcn_s_setprio(1);
    #pragma unroll
    for (int kkb = 0; kkb < 2; ++kkb)
      #pragma unroll
      for (int i = 0; i < 8; ++i)
        #pragma unroll
        for (int jx = 0; jx < 4; ++jx)
          acc[i][jx] = __builtin_amdgcn_mfma_f32_16x16x32_bf16(af[i][kkb], bf[jx][kkb], acc[i][jx], 0, 0, 0);
    __builtin_amdgcn_s_setprio(0);
    // stage(kt+1) (8 older loads) landed; stage(kt+2)'s 8 may stay in flight
    __asm__ volatile("s_waitcnt vmcnt(8)\n\ts_barrier" ::: "memory");
  }
  // drain ALL outstanding LDS-DMA before this WG can retire (LDS reassignment!)
  __asm__ volatile("s_waitcnt vmcnt(0)" ::: "memory");

  int rbase = r0 + wm * 128 + (lane >> 4) * 4;
  int cbase = c0 + wn * 64 + (lane & 15);
  #pragma unroll
  for (int i = 0; i < 8; ++i)
    #pragma unroll
    for (int jx = 0; jx < 4; ++jx)
      #pragma unroll
      for (int q = 0; q < 4; ++q)
        C[(size_t)(rbase + i * 16 + q) * 32000 + cbase + jx * 16] = acc[i][jx][q];
}

// ---------- launch ----------
extern "C" void kernel_launch(void* const* d_in, const int* in_sizes, int n_in,
                              void* d_out, int out_size, void* d_ws, size_t ws_size,
                              hipStream_t stream) {
  const int* tok = (const int*)d_in[0];
  const float* emb = (const float*)d_in[1];
  const float* Wx = (const float*)d_in[2];
  const float* Wh = (const float*)d_in[3];
  const float* bias = (const float*)d_in[4];
  const float* lmW = (const float*)d_in[5];
  float* out = (float*)d_out;

  const size_t OFF_LMW = 0;                       // bf16 lm_W: 65,536,000
  const size_t OFF_XW = 65536000;                 // f32 xw:   16,777,216
  const size_t OFF_HALL = OFF_XW + 16777216;      // bf16 h_all: 8,388,608
  const size_t OFF_HCMB = OFF_HALL + 8388608;     // u64 hcomb: 2*16*1024*8 = 262,144
  const size_t NEED = OFF_HCMB + 262144;
  if (ws_size < NEED) {
    sentinel_kernel<<<1, 1, 0, stream>>>(out);
    return;
  }
  char* ws = (char*)d_ws;
  unsigned short* lmW_bf = (unsigned short*)(ws + OFF_LMW);
  float* xw = (float*)(ws + OFF_XW);
  unsigned short* h_all = (unsigned short*)(ws + OFF_HALL);
  unsigned long long* hcomb = (unsigned long long*)(ws + OFF_HCMB);

  // tags must restart at 0 EVERY call (graph replay!)
  hipMemsetAsync(ws + OFF_HCMB, 0, 262144, stream);
  xwcvt_kernel<<<1536, 256, 0, stream>>>(tok, emb, Wx, bias, xw, lmW, lmW_bf);
  rec_kernel<<<256, 1024, 0, stream>>>(Wh, xw, tok, hcomb, h_all);
  gemm_kernel<<<2000, 512, 0, stream>>>(h_all, lmW_bf, out);
}